// Round 4
// baseline (41617.929 us; speedup 1.0000x reference)
//
#include <hip/hip_runtime.h>
#include <math.h>

using ushort_t = unsigned short;
using short8 = __attribute__((ext_vector_type(8))) short;
using floatx16 = __attribute__((ext_vector_type(16))) float;

constexpr int kB = 512, kT = 256, kH = 512, kHor = 64;
constexpr int NG = 4 * kH;  // 2048 packed gate rows
constexpr unsigned NBLK = 512;

__device__ __forceinline__ ushort_t f2bf(float v) {
  unsigned u = __builtin_bit_cast(unsigned, v);
  return (ushort_t)((u + 0x7FFFu + ((u >> 16) & 1u)) >> 16);
}
__device__ __forceinline__ float bf2f(ushort_t b) {
  unsigned u = (unsigned)b << 16;
  return __builtin_bit_cast(float, u);
}
__device__ __forceinline__ float sig_(float x) { return 1.0f / (1.0f + __expf(-x)); }

__device__ __forceinline__ void async16(const ushort_t* g, ushort_t* l) {
  __builtin_amdgcn_global_load_lds(
      (const __attribute__((address_space(1))) void*)g,
      (__attribute__((address_space(3))) void*)l, 16, 0, 0);
}

// Hand-rolled grid barrier (normal launch; 512 blocks co-resident by construction:
// LDS 70144*2 <= 163840, VGPR<=256 via launch_bounds -> 2 blocks/CU * 256 CU = 512).
__device__ __forceinline__ void grid_barrier(unsigned* cnt, unsigned* gen) {
  __syncthreads();
  if (threadIdx.x == 0) {
    __threadfence();   // release: L2 writeback, cross-XCD visibility of our stores
    unsigned g = __hip_atomic_load(gen, __ATOMIC_RELAXED, __HIP_MEMORY_SCOPE_AGENT);
    unsigned old = __hip_atomic_fetch_add(cnt, 1u, __ATOMIC_ACQ_REL, __HIP_MEMORY_SCOPE_AGENT);
    if (old == NBLK - 1u) {
      __hip_atomic_store(cnt, 0u, __ATOMIC_RELAXED, __HIP_MEMORY_SCOPE_AGENT);
      __hip_atomic_store(gen, g + 1u, __ATOMIC_RELEASE, __HIP_MEMORY_SCOPE_AGENT);
    } else {
      while (__hip_atomic_load(gen, __ATOMIC_RELAXED, __HIP_MEMORY_SCOPE_AGENT) == g)
        __builtin_amdgcn_s_sleep(2);
    }
    __threadfence();   // acquire: invalidate stale L1/L2 before reading peers' data
  }
  __syncthreads();
}

struct UnitP {
  const ushort_t *Whi, *Wlo;            // packed weights [r=j*4+g][k], stride Kw
  const ushort_t *B0hi, *B0lo;          // h source planes (B,H), k 0..511
  const ushort_t *B1hi, *B1lo;          // k 512..1023 (unit B)
  const float* bias;                    // packed [j*4+g]
  ushort_t *Hhi, *Hlo;                  // output h planes (B,H)
  int Kw;                               // 512 or 1024
};

struct PP {
  const ushort_t *w0e_hi, *w0e_lo, *w1e_hi, *w1e_lo;
  const ushort_t *w0d_hi, *w0d_lo, *w1d_hi, *w1d_lo;
  ushort_t *h0hi0, *h0hi1, *h0lo0, *h0lo1;
  ushort_t *h1hi0, *h1hi1, *h1lo0, *h1lo1;
  const float *be0, *be1, *bd0, *bd1, *wxe, *wxd;
  const float *x, *hW, *hb;
  float *ib0, *ib1, *out;
  unsigned *bar;                        // [0]=cnt [1]=gen
};

// One layer-step GEMM + LSTM cell for this block's fixed 64x64 tile.
// c-state lives in cr[4] (VGPRs) across the whole persistent run.
__device__ __forceinline__ void run_unit(
    const UnitP& U, bool isA, int mb, int nb, float* cr,
    const float* xsrc, int xmode, int tcol, const float* wx,
    float* outp, int ocol,
    float* inp_next, const float* headb, int do_init,
    const float* headW, float* head_acc, int do_head,
    ushort_t* sm, ushort_t* hshi, ushort_t* hslo)
{
  const int tid = threadIdx.x;
  const int m0blk = mb * 64;
  const int n0blk = nb * 64;
  const int nkt = U.Kw >> 6;

  const int wv = tid >> 6;
  const int ln = tid & 63;
  const int l31 = ln & 31;
  const int half = ln >> 5;
  const int wm = wv & 1, wn = wv >> 1;
  const int m0w = wm * 32, n0w = wn * 32;

  // staging invariants (wave wv stages plane wv: 0=Ahi 1=Alo 2=Bhi 3=Blo)
  const int r8 = ln >> 3;
  const int k8s = (ln & 7) ^ r8;
  const bool stA = wv < 2;
  const ushort_t* gsrcA = (wv == 0) ? U.Whi : U.Wlo;
  const ushort_t* b0p = (wv == 2) ? U.B0hi : U.B0lo;
  const ushort_t* b1p = (wv == 2) ? U.B1hi : U.B1lo;
  ushort_t* lwb = &sm[wv * 4096];

  auto issue = [&](int kt, int bufsel) {
    ushort_t* lb = lwb + bufsel * 16384;
    if (stA) {
      const ushort_t* g0 = gsrcA + (size_t)(m0blk + r8) * U.Kw + kt * 64 + k8s * 8;
      #pragma unroll
      for (int i = 0; i < 8; ++i)
        async16(g0 + (size_t)i * 8 * U.Kw, lb + i * 512);
    } else {
      const ushort_t* bsrc = (kt < 8) ? b0p : b1p;
      const int col0 = (kt & 7) * 64;
      const ushort_t* g0 = bsrc + (size_t)(n0blk + r8) * kH + col0 + k8s * 8;
      #pragma unroll
      for (int i = 0; i < 8; ++i)
        async16(g0 + (size_t)i * 8 * kH, lb + i * 512);
    }
  };

  floatx16 acc;
  #pragma unroll
  for (int i = 0; i < 16; ++i) acc[i] = 0.0f;

  issue(0, 0);

  for (int kt = 0; kt < nkt; ++kt) {
    const int cur = kt & 1;
    if (kt + 1 < nkt) {
      if (kt > 0) {           // WAR: everyone done computing buf[cur^1]
        asm volatile("" ::: "memory");
        __builtin_amdgcn_s_barrier();
        asm volatile("" ::: "memory");
      }
      issue(kt + 1, cur ^ 1);
      asm volatile("" ::: "memory");
      __builtin_amdgcn_s_waitcnt(0xF78);  // vmcnt(8): my cur-tile loads done
    } else {
      asm volatile("" ::: "memory");
      __builtin_amdgcn_s_waitcnt(0xF70);  // vmcnt(0)
    }
    asm volatile("" ::: "memory");
    __builtin_amdgcn_s_barrier();          // all waves' cur loads visible
    asm volatile("" ::: "memory");

    const ushort_t* base = &sm[cur * 16384];
    #pragma unroll
    for (int ks = 0; ks < 4; ++ks) {
      const int k8 = ks * 2 + half;
      const int qa = (m0w + l31) * 8 + (k8 ^ (l31 & 7));
      const int qb = (n0w + l31) * 8 + (k8 ^ (l31 & 7));
      short8 ahi = *(const short8*)(base + qa * 8);
      short8 alo = *(const short8*)(base + 4096 + qa * 8);
      short8 bhi = *(const short8*)(base + 8192 + qb * 8);
      short8 blo = *(const short8*)(base + 12288 + qb * 8);
      acc = __builtin_amdgcn_mfma_f32_32x32x16_bf16(alo, bhi, acc, 0, 0, 0);
      acc = __builtin_amdgcn_mfma_f32_32x32x16_bf16(ahi, blo, acc, 0, 0, 0);
      acc = __builtin_amdgcn_mfma_f32_32x32x16_bf16(ahi, bhi, acc, 0, 0, 0);
    }
  }

  // ---- epilogue: lane holds 4 j-groups x 4 gates for one n ----
  const int jt0 = mb * 16;
  const int ng = n0blk + n0w + l31;
  float xv = 0.0f;
  if (isA) xv = (xmode == 0) ? xsrc[(size_t)ng * kT + tcol] : xsrc[ng];

  #pragma unroll
  for (int rg = 0; rg < 4; ++rg) {
    const int jl = wm * 8 + rg * 2 + half;      // j within block's 16
    const int jg = jt0 + jl;
    const float4 bi = *(const float4*)&U.bias[jg * 4];
    float gi = acc[rg * 4 + 0] + bi.x;
    float gf = acc[rg * 4 + 1] + bi.y;
    float gg = acc[rg * 4 + 2] + bi.z;
    float go = acc[rg * 4 + 3] + bi.w;
    if (isA) {
      const float4 wx4 = *(const float4*)&wx[jg * 4];
      gi += xv * wx4.x; gf += xv * wx4.y; gg += xv * wx4.z; go += xv * wx4.w;
    }
    const float i_ = sig_(gi), f_ = sig_(gf), g_ = tanhf(gg), o_ = sig_(go);
    const float cn = f_ * cr[rg] + i_ * g_;
    cr[rg] = cn;
    const float hn = o_ * tanhf(cn);
    const ushort_t hhi = f2bf(hn);
    const ushort_t hlo = f2bf(hn - bf2f(hhi));
    const int nbk = n0w + l31;
    hshi[nbk * 18 + jl] = hhi;
    hslo[nbk * 18 + jl] = hlo;
  }
  __syncthreads();

  // coalesced h-plane write (B,H): 4 threads/row x 8B
  {
    const int nbk = tid >> 2;
    const int jq = (tid & 3) * 4;
    ushort4 vh, vl;
    vh.x = hshi[nbk * 18 + jq + 0]; vh.y = hshi[nbk * 18 + jq + 1];
    vh.z = hshi[nbk * 18 + jq + 2]; vh.w = hshi[nbk * 18 + jq + 3];
    vl.x = hslo[nbk * 18 + jq + 0]; vl.y = hslo[nbk * 18 + jq + 1];
    vl.z = hslo[nbk * 18 + jq + 2]; vl.w = hslo[nbk * 18 + jq + 3];
    *(ushort4*)&U.Hhi[(size_t)(n0blk + nbk) * kH + jt0 + jq] = vh;
    *(ushort4*)&U.Hlo[(size_t)(n0blk + nbk) * kH + jt0 + jq] = vl;
  }

  if (!isA) {
    if (do_head && tid < 64) {
      float s = 0.0f;
      #pragma unroll
      for (int jb = 0; jb < 16; ++jb)
        s += (bf2f(hshi[tid * 18 + jb]) + bf2f(hslo[tid * 18 + jb])) * headW[jt0 + jb];
      atomicAdd(&head_acc[n0blk + tid], s);
    }
  } else if (mb == 0 && tid < 64) {
    const int n = n0blk + tid;
    if (do_init) inp_next[n] = headb[0];
    if (ocol >= 0) outp[(size_t)n * kHor + ocol] = xsrc[n];
  }
}

__global__ __launch_bounds__(256, 2) void lstm_persist(PP P) {
  __shared__ __align__(16) ushort_t sm[32768];   // 2 buffers x 4 planes x 4096
  __shared__ ushort_t hshi[64 * 18];
  __shared__ ushort_t hslo[64 * 18];

  unsigned* bcnt = P.bar;
  unsigned* bgen = P.bar + 1;

  const int bx = blockIdx.x;
  const bool isA = bx < 256;
  const int bidx = isA ? bx : bx - 256;
  const int mb = bidx & 31;
  const int nb = bidx >> 5;

  ushort_t* h0hi[2] = {P.h0hi0, P.h0hi1};
  ushort_t* h0lo[2] = {P.h0lo0, P.h0lo1};
  ushort_t* h1hi[2] = {P.h1hi0, P.h1hi1};
  ushort_t* h1lo[2] = {P.h1lo0, P.h1lo1};

  float cr[4] = {0.f, 0.f, 0.f, 0.f};   // persistent c-state (c0 for A, c1 for B)

  // ---------- encoder: wavefront phases p=0..256 (L0[p] || L1[p-1]) ----------
  for (int p = 0; p <= 256; ++p) {
    const int rd = p & 1, wr = (p + 1) & 1;
    if (isA && p < 256) {
      UnitP U = {P.w0e_hi, P.w0e_lo, h0hi[rd], h0lo[rd], h0hi[rd], h0lo[rd],
                 P.be0, h0hi[wr], h0lo[wr], 512};
      run_unit(U, true, mb, nb, cr, P.x, 0, p, P.wxe,
               nullptr, -1, nullptr, P.hb, 0, nullptr, nullptr, 0,
               sm, hshi, hslo);
    } else if (!isA && p >= 1) {
      UnitP U = {P.w1e_hi, P.w1e_lo, h0hi[rd], h0lo[rd], h1hi[rd], h1lo[rd],
                 P.be1, h1hi[wr], h1lo[wr], 1024};
      run_unit(U, false, mb, nb, cr, nullptr, 0, 0, nullptr,
               nullptr, -1, nullptr, P.hb, 0, nullptr, nullptr, 0,
               sm, hshi, hslo);
    }
    grid_barrier(bcnt, bgen);
  }
  // h0 final parity 0, h1 final parity 1

  // ---------- decoder: 2 phases per step ----------
  for (int t = 0; t < kHor; ++t) {
    const int r0 = t & 1, w0i = (t + 1) & 1;
    const int r1 = (t + 1) & 1, w1i = t & 1;
    float* ibr = (t & 1) ? P.ib1 : P.ib0;
    float* ibw = ((t + 1) & 1) ? P.ib1 : P.ib0;

    if (isA) {
      UnitP U = {P.w0d_hi, P.w0d_lo, h0hi[r0], h0lo[r0], h0hi[r0], h0lo[r0],
                 P.bd0, h0hi[w0i], h0lo[w0i], 512};
      if (t == 0)
        run_unit(U, true, mb, nb, cr, P.x, 0, 255, P.wxd,
                 nullptr, -1, ibw, P.hb, 1, nullptr, nullptr, 0,
                 sm, hshi, hslo);
      else
        run_unit(U, true, mb, nb, cr, ibr, 1, 0, P.wxd,
                 P.out, t - 1, ibw, P.hb, 1, nullptr, nullptr, 0,
                 sm, hshi, hslo);
    }
    grid_barrier(bcnt, bgen);

    if (!isA) {
      UnitP U = {P.w1d_hi, P.w1d_lo, h0hi[w0i], h0lo[w0i], h1hi[r1], h1lo[r1],
                 P.bd1, h1hi[w1i], h1lo[w1i], 1024};
      run_unit(U, false, mb, nb, cr, nullptr, 0, 0, nullptr,
               nullptr, -1, nullptr, P.hb, 0, P.hW, ibw, 1,
               sm, hshi, hslo);
    }
    grid_barrier(bcnt, bgen);
  }

  // final output column: out[:,63] = ib0 (head of t=63 accumulated into ib0)
  if (bx == 0) {
    for (int n = threadIdx.x; n < kB; n += 256)
      P.out[(size_t)n * kHor + 63] = P.ib0[n];
  }
}

// ---- prep kernels ----
__global__ void prep_w(const float* __restrict__ s0, const float* __restrict__ s1,
                       ushort_t* __restrict__ hi, ushort_t* __restrict__ lo, int Kw) {
  const int k = blockIdx.x * 256 + threadIdx.x;
  const int r = blockIdx.y;                 // packed row j*4+g
  const int j = r >> 2, g = r & 3;
  const int srow = g * kH + j;
  const float v = (k < kH) ? s0[(size_t)srow * kH + k]
                           : s1[(size_t)srow * kH + (k - kH)];
  const ushort_t h = f2bf(v);
  const ushort_t l = f2bf(v - bf2f(h));
  hi[(size_t)r * Kw + k] = h;
  lo[(size_t)r * Kw + k] = l;
}

__global__ void prep_vec(const float* __restrict__ src, float* __restrict__ dst) {
  const int t = blockIdx.x * 256 + threadIdx.x;   // 2048
  const int j = t >> 2, g = t & 3;
  dst[t] = src[g * kH + j];
}

__global__ void init_zero(ushort_t* p0, ushort_t* p1, ushort_t* p2, ushort_t* p3,
                          ushort_t* p4, ushort_t* p5, ushort_t* p6, ushort_t* p7,
                          unsigned* bar) {
  const int i = blockIdx.x * 256 + threadIdx.x;   // 262144
  p0[i] = 0; p1[i] = 0; p2[i] = 0; p3[i] = 0;
  p4[i] = 0; p5[i] = 0; p6[i] = 0; p7[i] = 0;
  if (i < 8) bar[i] = 0u;
}

extern "C" void kernel_launch(void* const* d_in, const int* in_sizes, int n_in,
                              void* d_out, int out_size, void* d_ws, size_t ws_size,
                              hipStream_t stream) {
  const float* x     = (const float*)d_in[0];
  const float* eWih0 = (const float*)d_in[1];
  const float* eWhh0 = (const float*)d_in[2];
  const float* eb0   = (const float*)d_in[3];
  const float* eWih1 = (const float*)d_in[4];
  const float* eWhh1 = (const float*)d_in[5];
  const float* eb1   = (const float*)d_in[6];
  const float* dWih0 = (const float*)d_in[7];
  const float* dWhh0 = (const float*)d_in[8];
  const float* db0   = (const float*)d_in[9];
  const float* dWih1 = (const float*)d_in[10];
  const float* dWhh1 = (const float*)d_in[11];
  const float* db1   = (const float*)d_in[12];
  const float* hW    = (const float*)d_in[13];
  const float* hb    = (const float*)d_in[14];
  float* out = (float*)d_out;

  char* w = (char*)d_ws;
  size_t off = 0;
  auto aus = [&](size_t n) { ushort_t* p = (ushort_t*)(w + off); off += ((n * 2 + 255) & ~(size_t)255); return p; };
  auto afl = [&](size_t n) { float* p = (float*)(w + off); off += ((n * 4 + 255) & ~(size_t)255); return p; };

  ushort_t* w0e_hi = aus((size_t)NG * 512); ushort_t* w0e_lo = aus((size_t)NG * 512);
  ushort_t* w1e_hi = aus((size_t)NG * 1024); ushort_t* w1e_lo = aus((size_t)NG * 1024);
  ushort_t* w0d_hi = aus((size_t)NG * 512); ushort_t* w0d_lo = aus((size_t)NG * 512);
  ushort_t* w1d_hi = aus((size_t)NG * 1024); ushort_t* w1d_lo = aus((size_t)NG * 1024);
  ushort_t* h0hi[2] = {aus(kB * kH), aus(kB * kH)};
  ushort_t* h0lo[2] = {aus(kB * kH), aus(kB * kH)};
  ushort_t* h1hi[2] = {aus(kB * kH), aus(kB * kH)};
  ushort_t* h1lo[2] = {aus(kB * kH), aus(kB * kH)};
  float* be0 = afl(NG); float* be1 = afl(NG);
  float* bd0 = afl(NG); float* bd1 = afl(NG);
  float* wxe = afl(NG); float* wxd = afl(NG);
  float* ib0 = afl(kB); float* ib1 = afl(kB);
  unsigned* bar = (unsigned*)afl(8);

  prep_w<<<dim3(2, NG), 256, 0, stream>>>(eWhh0, eWhh0, w0e_hi, w0e_lo, 512);
  prep_w<<<dim3(4, NG), 256, 0, stream>>>(eWih1, eWhh1, w1e_hi, w1e_lo, 1024);
  prep_w<<<dim3(2, NG), 256, 0, stream>>>(dWhh0, dWhh0, w0d_hi, w0d_lo, 512);
  prep_w<<<dim3(4, NG), 256, 0, stream>>>(dWih1, dWhh1, w1d_hi, w1d_lo, 1024);
  prep_vec<<<8, 256, 0, stream>>>(eb0, be0);
  prep_vec<<<8, 256, 0, stream>>>(eb1, be1);
  prep_vec<<<8, 256, 0, stream>>>(db0, bd0);
  prep_vec<<<8, 256, 0, stream>>>(db1, bd1);
  prep_vec<<<8, 256, 0, stream>>>(eWih0, wxe);
  prep_vec<<<8, 256, 0, stream>>>(dWih0, wxd);
  init_zero<<<1024, 256, 0, stream>>>(h0hi[0], h0hi[1], h0lo[0], h0lo[1],
                                      h1hi[0], h1hi[1], h1lo[0], h1lo[1], bar);

  PP P;
  P.w0e_hi = w0e_hi; P.w0e_lo = w0e_lo; P.w1e_hi = w1e_hi; P.w1e_lo = w1e_lo;
  P.w0d_hi = w0d_hi; P.w0d_lo = w0d_lo; P.w1d_hi = w1d_hi; P.w1d_lo = w1d_lo;
  P.h0hi0 = h0hi[0]; P.h0hi1 = h0hi[1]; P.h0lo0 = h0lo[0]; P.h0lo1 = h0lo[1];
  P.h1hi0 = h1hi[0]; P.h1hi1 = h1hi[1]; P.h1lo0 = h1lo[0]; P.h1lo1 = h1lo[1];
  P.be0 = be0; P.be1 = be1; P.bd0 = bd0; P.bd1 = bd1; P.wxe = wxe; P.wxd = wxd;
  P.x = x; P.hW = hW; P.hb = hb;
  P.ib0 = ib0; P.ib1 = ib1; P.out = out;
  P.bar = bar;

  lstm_persist<<<dim3(NBLK), dim3(256), 0, stream>>>(P);
}

// Round 5
// 8797.150 us; speedup vs baseline: 4.7308x; 4.7308x over previous
//
#include <hip/hip_runtime.h>
#include <math.h>

using ushort_t = unsigned short;
using ull = unsigned long long;
using short8 = __attribute__((ext_vector_type(8))) short;
using floatx16 = __attribute__((ext_vector_type(16))) float;

constexpr int kB = 512, kT = 256, kH = 512, kHor = 64;
constexpr int NG = 4 * kH;
constexpr int NBLK = 256;

// LDS plane offsets (shorts): per buffer 6 planes x 4096
constexpr int P_A0 = 0;        // a0 hi; lo at +4096
constexpr int P_A1 = 8192;     // a1 hi; lo at +4096
constexpr int P_B  = 16384;    // b  hi; lo at +4096
constexpr int BUFS = 24576;    // buffer stride in shorts (2 buffers)

__device__ __forceinline__ ushort_t f2bf(float v) {
  unsigned u = __builtin_bit_cast(unsigned, v);
  return (ushort_t)((u + 0x7FFFu + ((u >> 16) & 1u)) >> 16);
}
__device__ __forceinline__ float bf2f(ushort_t b) {
  unsigned u = (unsigned)b << 16;
  return __builtin_bit_cast(float, u);
}
__device__ __forceinline__ float sig_(float x) { return 1.0f / (1.0f + __expf(-x)); }

__device__ __forceinline__ void async16(const ushort_t* g, ushort_t* l) {
  __builtin_amdgcn_global_load_lds(
      (const __attribute__((address_space(1))) void*)g,
      (__attribute__((address_space(3))) void*)l, 16, 0, 0);
}

__device__ __forceinline__ ull ald64(const void* p) {
  return __hip_atomic_load((const ull*)p, __ATOMIC_RELAXED, __HIP_MEMORY_SCOPE_AGENT);
}
__device__ __forceinline__ void ast64(void* p, ull v) {
  __hip_atomic_store((ull*)p, v, __ATOMIC_RELAXED, __HIP_MEMORY_SCOPE_AGENT);
}
__device__ __forceinline__ void astf(float* p, float v) {
  __hip_atomic_store(p, v, __ATOMIC_RELAXED, __HIP_MEMORY_SCOPE_AGENT);
}
__device__ __forceinline__ unsigned aldu(const unsigned* p) {
  return __hip_atomic_load(p, __ATOMIC_RELAXED, __HIP_MEMORY_SCOPE_AGENT);
}
__device__ __forceinline__ void astu(unsigned* p, unsigned v) {
  __hip_atomic_store(p, v, __ATOMIC_RELAXED, __HIP_MEMORY_SCOPE_AGENT);
}

struct PP {
  const ushort_t *w0e_hi, *w0e_lo, *w1e_hi, *w1e_lo;
  const ushort_t *w0d_hi, *w0d_lo, *w1d_hi, *w1d_lo;
  ushort_t *h0hi0, *h0hi1, *h0lo0, *h0lo1;
  ushort_t *h1hi0, *h1hi1, *h1lo0, *h1lo1;
  const float *be0, *be1, *bd0, *bd1, *wxe, *wxd;
  const float *x, *headW, *hb;
  float *hpart;        // [n][32] per-mb head partials
  float *out;
  unsigned *slots;     // [256] completed-phase counters
};

struct Ph {
  const ushort_t *w0hi, *w0lo, *w1hi, *w1lo;
  const ushort_t *b0hi, *b0lo, *b1hi, *b1lo;
  const float *bias0, *wx0, *bias1;
  ushort_t *H0hi, *H0lo, *H1hi, *H1lo;
  int has0, has1, nkt;
  int xmode;    // 0: x[:,tcol]; 1: head from hpart
  int tcol;
  int outcol;   // >=0: lanes wm==0 write out[:,outcol] = xv
  int do_head;  // L1 epilogue stores head partials
};

__global__ __launch_bounds__(256) void lstm_persist(PP P) {
  __shared__ __align__(16) ushort_t sm[2 * BUFS];     // 96 KB
  __shared__ ushort_t hshi[64 * 18];
  __shared__ ushort_t hslo[64 * 18];

  const int tid = threadIdx.x;
  const int bx = blockIdx.x;
  const int mb = bx & 31;
  const int nb = bx >> 5;
  const int m0blk = mb * 64;
  const int n0blk = nb * 64;

  const int wv = tid >> 6;
  const int ln = tid & 63;
  const int l31 = ln & 31;
  const int half = ln >> 5;
  const int wm = wv & 1, wn = wv >> 1;
  const int m0w = wm * 32, n0w = wn * 32;
  const int r8 = ln >> 3;
  const int k8s = (ln & 7) ^ r8;
  const int ng = n0blk + n0w + l31;

  ushort_t* h0hi[2] = {P.h0hi0, P.h0hi1};
  ushort_t* h0lo[2] = {P.h0lo0, P.h0lo1};
  ushort_t* h1hi[2] = {P.h1hi0, P.h1hi1};
  ushort_t* h1lo[2] = {P.h1lo0, P.h1lo1};

  float cr0[4] = {0.f, 0.f, 0.f, 0.f};
  float cr1[4] = {0.f, 0.f, 0.f, 0.f};
  unsigned phase = 0;

  auto gbar = [&]() {
    __builtin_amdgcn_s_waitcnt(0);      // all my VMEM (atomic stores) done at L3
    __syncthreads();
    ++phase;
    if (tid == 0) astu(&P.slots[bx], phase);
    asm volatile("" ::: "memory");
    while (aldu(&P.slots[tid]) < phase) __builtin_amdgcn_s_sleep(2);
    asm volatile("" ::: "memory");
    __syncthreads();
  };

  auto cell_epi = [&](floatx16& acc, float* cr, const float* bias, const float* wx,
                      bool useX, float xv, ushort_t* Hhi, ushort_t* Hlo) {
    #pragma unroll
    for (int rg = 0; rg < 4; ++rg) {
      const int jl = wm * 8 + rg * 2 + half;
      const int jg = mb * 16 + jl;
      const float4 bi = *(const float4*)&bias[jg * 4];
      float gi = acc[rg * 4 + 0] + bi.x;
      float gf = acc[rg * 4 + 1] + bi.y;
      float gg = acc[rg * 4 + 2] + bi.z;
      float go = acc[rg * 4 + 3] + bi.w;
      if (useX) {
        const float4 wx4 = *(const float4*)&wx[jg * 4];
        gi += xv * wx4.x; gf += xv * wx4.y; gg += xv * wx4.z; go += xv * wx4.w;
      }
      const float i_ = sig_(gi), f_ = sig_(gf), g_ = tanhf(gg), o_ = sig_(go);
      const float cn = f_ * cr[rg] + i_ * g_;
      cr[rg] = cn;
      const float hn = o_ * tanhf(cn);
      const ushort_t hhi = f2bf(hn);
      const ushort_t hlo = f2bf(hn - bf2f(hhi));
      const int nbk = n0w + l31;
      hshi[nbk * 18 + jl] = hhi;
      hslo[nbk * 18 + jl] = hlo;
    }
    __syncthreads();
    {
      const int nbk = tid >> 2, jq = (tid & 3) * 4;
      ull hv = (ull)hshi[nbk * 18 + jq] | ((ull)hshi[nbk * 18 + jq + 1] << 16)
             | ((ull)hshi[nbk * 18 + jq + 2] << 32) | ((ull)hshi[nbk * 18 + jq + 3] << 48);
      ull lv = (ull)hslo[nbk * 18 + jq] | ((ull)hslo[nbk * 18 + jq + 1] << 16)
             | ((ull)hslo[nbk * 18 + jq + 2] << 32) | ((ull)hslo[nbk * 18 + jq + 3] << 48);
      ast64(&Hhi[(size_t)(n0blk + nbk) * kH + mb * 16 + jq], hv);
      ast64(&Hlo[(size_t)(n0blk + nbk) * kH + mb * 16 + jq], lv);
    }
  };

  auto run_phase = [&](const Ph& ph) {
    floatx16 acc0, acc1;
    #pragma unroll
    for (int i = 0; i < 16; ++i) { acc0[i] = 0.f; acc1[i] = 0.f; }

    auto dma_kt = [&](int kt, int buf) {
      if (wv <= 1) {
        ushort_t* bb = &sm[buf * BUFS];
        if (ph.has0 && kt < 8) {
          const ushort_t* w = wv ? ph.w0lo : ph.w0hi;
          const ushort_t* g0 = w + (size_t)(m0blk + r8) * 512 + kt * 64 + k8s * 8;
          ushort_t* lb = bb + P_A0 + wv * 4096;
          #pragma unroll
          for (int i = 0; i < 8; ++i) async16(g0 + (size_t)i * 8 * 512, lb + i * 512);
        }
        if (ph.has1) {
          const ushort_t* w = wv ? ph.w1lo : ph.w1hi;
          const ushort_t* g0 = w + (size_t)(m0blk + r8) * 1024 + kt * 64 + k8s * 8;
          ushort_t* lb = bb + P_A1 + wv * 4096;
          #pragma unroll
          for (int i = 0; i < 8; ++i) async16(g0 + (size_t)i * 8 * 1024, lb + i * 512);
        }
      }
    };
    auto bload = [&](int kt, ull* br) {
      if (wv >= 2) {
        const ushort_t* s = (kt < 8) ? (wv == 2 ? ph.b0hi : ph.b0lo)
                                     : (wv == 2 ? ph.b1hi : ph.b1lo);
        const int col0 = (kt & 7) * 64;
        const ushort_t* g0 = s + (size_t)(n0blk + r8) * kH + col0 + k8s * 8;
        #pragma unroll
        for (int i = 0; i < 8; ++i) {
          const ushort_t* gp = g0 + (size_t)i * 8 * kH;
          br[2 * i]     = ald64(gp);
          br[2 * i + 1] = ald64(gp + 4);
        }
      }
    };
    auto bwrite = [&](int buf, const ull* br) {
      if (wv >= 2) {
        ushort_t* lb = &sm[buf * BUFS] + P_B + (wv - 2) * 4096;
        #pragma unroll
        for (int i = 0; i < 8; ++i) {
          int4 v;
          v.x = (int)(unsigned)br[2 * i];
          v.y = (int)(unsigned)(br[2 * i] >> 32);
          v.z = (int)(unsigned)br[2 * i + 1];
          v.w = (int)(unsigned)(br[2 * i + 1] >> 32);
          *(int4*)(lb + i * 512 + ln * 8) = v;
        }
      }
    };
    auto compute = [&](int kt, int buf) {
      const ushort_t* base = &sm[buf * BUFS];
      #pragma unroll
      for (int ks = 0; ks < 4; ++ks) {
        const int k8 = ks * 2 + half;
        const int sw = k8 ^ (l31 & 7);
        const int qa = ((m0w + l31) * 8 + sw) * 8;
        const int qb = ((n0w + l31) * 8 + sw) * 8;
        short8 bhi = *(const short8*)(base + P_B + qb);
        short8 blo = *(const short8*)(base + P_B + 4096 + qb);
        if (ph.has0 && kt < 8) {
          short8 ahi = *(const short8*)(base + P_A0 + qa);
          short8 alo = *(const short8*)(base + P_A0 + 4096 + qa);
          acc0 = __builtin_amdgcn_mfma_f32_32x32x16_bf16(alo, bhi, acc0, 0, 0, 0);
          acc0 = __builtin_amdgcn_mfma_f32_32x32x16_bf16(ahi, blo, acc0, 0, 0, 0);
          acc0 = __builtin_amdgcn_mfma_f32_32x32x16_bf16(ahi, bhi, acc0, 0, 0, 0);
        }
        if (ph.has1) {
          short8 ahi = *(const short8*)(base + P_A1 + qa);
          short8 alo = *(const short8*)(base + P_A1 + 4096 + qa);
          acc1 = __builtin_amdgcn_mfma_f32_32x32x16_bf16(alo, bhi, acc1, 0, 0, 0);
          acc1 = __builtin_amdgcn_mfma_f32_32x32x16_bf16(ahi, blo, acc1, 0, 0, 0);
          acc1 = __builtin_amdgcn_mfma_f32_32x32x16_bf16(ahi, bhi, acc1, 0, 0, 0);
        }
      }
    };

    ull br[16];
    bload(0, br);
    dma_kt(0, 0);
    bwrite(0, br);
    __syncthreads();
    for (int kt = 0; kt < ph.nkt; ++kt) {
      const int cur = kt & 1, nxt = cur ^ 1;
      const bool more = (kt + 1) < ph.nkt;
      if (more) { bload(kt + 1, br); dma_kt(kt + 1, nxt); }
      compute(kt, cur);
      if (more) bwrite(nxt, br);
      __syncthreads();
    }

    if (ph.has0) {
      float xv;
      if (ph.xmode == 0) {
        xv = P.x[(size_t)ng * kT + ph.tcol];
      } else {
        float s = P.hb[0];
        const float* hp = &P.hpart[(size_t)ng * 32];
        #pragma unroll
        for (int i = 0; i < 16; ++i) {
          ull v = ald64(hp + 2 * i);
          s += __builtin_bit_cast(float, (unsigned)v)
             + __builtin_bit_cast(float, (unsigned)(v >> 32));
        }
        xv = s;
      }
      cell_epi(acc0, cr0, ph.bias0, ph.wx0, true, xv, ph.H0hi, ph.H0lo);
      if (ph.outcol >= 0 && wm == 0)
        P.out[(size_t)ng * kHor + ph.outcol] = xv;
      __syncthreads();
    }
    if (ph.has1) {
      cell_epi(acc1, cr1, ph.bias1, nullptr, false, 0.f, ph.H1hi, ph.H1lo);
      if (ph.do_head && tid < 64) {
        float s = 0.f;
        #pragma unroll
        for (int jb = 0; jb < 16; ++jb)
          s += (bf2f(hshi[tid * 18 + jb]) + bf2f(hslo[tid * 18 + jb]))
               * P.headW[mb * 16 + jb];
        astf(&P.hpart[(size_t)(n0blk + tid) * 32 + mb], s);
      }
      __syncthreads();
    }
  };

  // ---------- encoder: merged wavefront L0[p] || L1[p-1] ----------
  for (int p = 0; p <= 256; ++p) {
    const int rd = p & 1, wr = rd ^ 1;
    Ph ph = {};
    ph.has0 = (p < 256); ph.has1 = (p >= 1);
    ph.nkt = ph.has1 ? 16 : 8;
    ph.w0hi = P.w0e_hi; ph.w0lo = P.w0e_lo;
    ph.w1hi = P.w1e_hi; ph.w1lo = P.w1e_lo;
    ph.b0hi = h0hi[rd]; ph.b0lo = h0lo[rd];
    ph.b1hi = h1hi[rd]; ph.b1lo = h1lo[rd];
    ph.bias0 = P.be0; ph.wx0 = P.wxe; ph.bias1 = P.be1;
    ph.H0hi = h0hi[wr]; ph.H0lo = h0lo[wr];
    ph.H1hi = h1hi[wr]; ph.H1lo = h1lo[wr];
    ph.xmode = 0; ph.tcol = (p < 256) ? p : 0;
    ph.outcol = -1; ph.do_head = 0;
    run_phase(ph);
    gbar();
  }
  // h0 final parity 0, h1 final parity 1

  // ---------- decoder ----------
  for (int t = 0; t < kHor; ++t) {
    const int r0 = t & 1, w0 = r0 ^ 1;
    const int r1 = (t + 1) & 1, w1 = t & 1;
    {
      Ph a = {};
      a.has0 = 1; a.has1 = 0; a.nkt = 8;
      a.w0hi = P.w0d_hi; a.w0lo = P.w0d_lo;
      a.b0hi = h0hi[r0]; a.b0lo = h0lo[r0];
      a.bias0 = P.bd0; a.wx0 = P.wxd;
      a.H0hi = h0hi[w0]; a.H0lo = h0lo[w0];
      a.xmode = (t == 0) ? 0 : 1; a.tcol = 255;
      a.outcol = (t >= 1) ? (t - 1) : -1;
      a.do_head = 0;
      run_phase(a);
      gbar();
    }
    {
      Ph b = {};
      b.has0 = 0; b.has1 = 1; b.nkt = 16;
      b.w1hi = P.w1d_hi; b.w1lo = P.w1d_lo;
      b.b0hi = h0hi[w0]; b.b0lo = h0lo[w0];
      b.b1hi = h1hi[r1]; b.b1lo = h1lo[r1];
      b.bias1 = P.bd1;
      b.H1hi = h1hi[w1]; b.H1lo = h1lo[w1];
      b.xmode = 0; b.tcol = 0; b.outcol = -1; b.do_head = 1;
      run_phase(b);
      gbar();
    }
  }

  // final output column 63
  if (mb == 0 && tid < 64) {
    const int n = n0blk + tid;
    float s = P.hb[0];
    const float* hp = &P.hpart[(size_t)n * 32];
    #pragma unroll
    for (int i = 0; i < 16; ++i) {
      ull v = ald64(hp + 2 * i);
      s += __builtin_bit_cast(float, (unsigned)v)
         + __builtin_bit_cast(float, (unsigned)(v >> 32));
    }
    P.out[(size_t)n * kHor + 63] = s;
  }
}

// ---- prep kernels ----
__global__ void prep_w(const float* __restrict__ s0, const float* __restrict__ s1,
                       ushort_t* __restrict__ hi, ushort_t* __restrict__ lo, int Kw) {
  const int k = blockIdx.x * 256 + threadIdx.x;
  const int r = blockIdx.y;                 // packed row j*4+g
  const int j = r >> 2, g = r & 3;
  const int srow = g * kH + j;
  const float v = (k < kH) ? s0[(size_t)srow * kH + k]
                           : s1[(size_t)srow * kH + (k - kH)];
  const ushort_t h = f2bf(v);
  const ushort_t l = f2bf(v - bf2f(h));
  hi[(size_t)r * Kw + k] = h;
  lo[(size_t)r * Kw + k] = l;
}

__global__ void prep_vec(const float* __restrict__ src, float* __restrict__ dst) {
  const int t = blockIdx.x * 256 + threadIdx.x;   // 2048
  const int j = t >> 2, g = t & 3;
  dst[t] = src[g * kH + j];
}

__global__ void init_zero(ushort_t* p0, ushort_t* p1, ushort_t* p2, ushort_t* p3,
                          ushort_t* p4, ushort_t* p5, ushort_t* p6, ushort_t* p7,
                          unsigned* slots) {
  const int i = blockIdx.x * 256 + threadIdx.x;   // 262144
  p0[i] = 0; p1[i] = 0; p2[i] = 0; p3[i] = 0;
  p4[i] = 0; p5[i] = 0; p6[i] = 0; p7[i] = 0;
  if (i < NBLK) slots[i] = 0u;
}

extern "C" void kernel_launch(void* const* d_in, const int* in_sizes, int n_in,
                              void* d_out, int out_size, void* d_ws, size_t ws_size,
                              hipStream_t stream) {
  const float* x     = (const float*)d_in[0];
  const float* eWih0 = (const float*)d_in[1];
  const float* eWhh0 = (const float*)d_in[2];
  const float* eb0   = (const float*)d_in[3];
  const float* eWih1 = (const float*)d_in[4];
  const float* eWhh1 = (const float*)d_in[5];
  const float* eb1   = (const float*)d_in[6];
  const float* dWih0 = (const float*)d_in[7];
  const float* dWhh0 = (const float*)d_in[8];
  const float* db0   = (const float*)d_in[9];
  const float* dWih1 = (const float*)d_in[10];
  const float* dWhh1 = (const float*)d_in[11];
  const float* db1   = (const float*)d_in[12];
  const float* hW    = (const float*)d_in[13];
  const float* hb    = (const float*)d_in[14];
  float* out = (float*)d_out;

  char* w = (char*)d_ws;
  size_t off = 0;
  auto aus = [&](size_t n) { ushort_t* p = (ushort_t*)(w + off); off += ((n * 2 + 255) & ~(size_t)255); return p; };
  auto afl = [&](size_t n) { float* p = (float*)(w + off); off += ((n * 4 + 255) & ~(size_t)255); return p; };

  ushort_t* w0e_hi = aus((size_t)NG * 512);  ushort_t* w0e_lo = aus((size_t)NG * 512);
  ushort_t* w1e_hi = aus((size_t)NG * 1024); ushort_t* w1e_lo = aus((size_t)NG * 1024);
  ushort_t* w0d_hi = aus((size_t)NG * 512);  ushort_t* w0d_lo = aus((size_t)NG * 512);
  ushort_t* w1d_hi = aus((size_t)NG * 1024); ushort_t* w1d_lo = aus((size_t)NG * 1024);
  ushort_t* h0hi[2] = {aus(kB * kH), aus(kB * kH)};
  ushort_t* h0lo[2] = {aus(kB * kH), aus(kB * kH)};
  ushort_t* h1hi[2] = {aus(kB * kH), aus(kB * kH)};
  ushort_t* h1lo[2] = {aus(kB * kH), aus(kB * kH)};
  float* be0 = afl(NG); float* be1 = afl(NG);
  float* bd0 = afl(NG); float* bd1 = afl(NG);
  float* wxe = afl(NG); float* wxd = afl(NG);
  float* hpart = afl((size_t)kB * 32);
  unsigned* slots = (unsigned*)afl(NBLK);

  prep_w<<<dim3(2, NG), 256, 0, stream>>>(eWhh0, eWhh0, w0e_hi, w0e_lo, 512);
  prep_w<<<dim3(4, NG), 256, 0, stream>>>(eWih1, eWhh1, w1e_hi, w1e_lo, 1024);
  prep_w<<<dim3(2, NG), 256, 0, stream>>>(dWhh0, dWhh0, w0d_hi, w0d_lo, 512);
  prep_w<<<dim3(4, NG), 256, 0, stream>>>(dWih1, dWhh1, w1d_hi, w1d_lo, 1024);
  prep_vec<<<8, 256, 0, stream>>>(eb0, be0);
  prep_vec<<<8, 256, 0, stream>>>(eb1, be1);
  prep_vec<<<8, 256, 0, stream>>>(db0, bd0);
  prep_vec<<<8, 256, 0, stream>>>(db1, bd1);
  prep_vec<<<8, 256, 0, stream>>>(eWih0, wxe);
  prep_vec<<<8, 256, 0, stream>>>(dWih0, wxd);
  init_zero<<<1024, 256, 0, stream>>>(h0hi[0], h0hi[1], h0lo[0], h0lo[1],
                                      h1hi[0], h1hi[1], h1lo[0], h1lo[1], slots);

  PP P;
  P.w0e_hi = w0e_hi; P.w0e_lo = w0e_lo; P.w1e_hi = w1e_hi; P.w1e_lo = w1e_lo;
  P.w0d_hi = w0d_hi; P.w0d_lo = w0d_lo; P.w1d_hi = w1d_hi; P.w1d_lo = w1d_lo;
  P.h0hi0 = h0hi[0]; P.h0hi1 = h0hi[1]; P.h0lo0 = h0lo[0]; P.h0lo1 = h0lo[1];
  P.h1hi0 = h1hi[0]; P.h1hi1 = h1hi[1]; P.h1lo0 = h1lo[0]; P.h1lo1 = h1lo[1];
  P.be0 = be0; P.be1 = be1; P.bd0 = bd0; P.bd1 = bd1; P.wxe = wxe; P.wxd = wxd;
  P.x = x; P.headW = hW; P.hb = hb;
  P.hpart = hpart; P.out = out; P.slots = slots;

  lstm_persist<<<dim3(NBLK), dim3(256), 0, stream>>>(P);
}

// Round 6
// 8671.735 us; speedup vs baseline: 4.7993x; 1.0145x over previous
//
#include <hip/hip_runtime.h>
#include <math.h>

using ushort_t = unsigned short;
using ull = unsigned long long;
using short8 = __attribute__((ext_vector_type(8))) short;
using floatx16 = __attribute__((ext_vector_type(16))) float;

constexpr int kB = 512, kT = 256, kH = 512, kHor = 64;
constexpr int NG = 4 * kH;
constexpr int NBLK = 256;

// LDS plane offsets (shorts): per buffer 6 planes x 4096
constexpr int P_A0 = 0;        // a0 hi; lo at +4096
constexpr int P_A1 = 8192;     // a1 hi; lo at +4096
constexpr int P_B  = 16384;    // b  hi; lo at +4096
constexpr int BUFS = 24576;    // buffer stride in shorts (2 buffers)

__device__ __forceinline__ ushort_t f2bf(float v) {
  unsigned u = __builtin_bit_cast(unsigned, v);
  return (ushort_t)((u + 0x7FFFu + ((u >> 16) & 1u)) >> 16);
}
__device__ __forceinline__ float bf2f(ushort_t b) {
  unsigned u = (unsigned)b << 16;
  return __builtin_bit_cast(float, u);
}
__device__ __forceinline__ float sig_(float x) { return 1.0f / (1.0f + __expf(-x)); }

__device__ __forceinline__ void async16(const ushort_t* g, ushort_t* l) {
  __builtin_amdgcn_global_load_lds(
      (const __attribute__((address_space(1))) void*)g,
      (__attribute__((address_space(3))) void*)l, 16, 0, 0);
}

__device__ __forceinline__ ull ald64(const void* p) {
  return __hip_atomic_load((const ull*)p, __ATOMIC_RELAXED, __HIP_MEMORY_SCOPE_AGENT);
}
__device__ __forceinline__ void ast64(void* p, ull v) {
  __hip_atomic_store((ull*)p, v, __ATOMIC_RELAXED, __HIP_MEMORY_SCOPE_AGENT);
}
__device__ __forceinline__ void astf(float* p, float v) {
  __hip_atomic_store(p, v, __ATOMIC_RELAXED, __HIP_MEMORY_SCOPE_AGENT);
}
__device__ __forceinline__ unsigned aldu(const unsigned* p) {
  return __hip_atomic_load(p, __ATOMIC_RELAXED, __HIP_MEMORY_SCOPE_AGENT);
}
__device__ __forceinline__ void astu(unsigned* p, unsigned v) {
  __hip_atomic_store(p, v, __ATOMIC_RELAXED, __HIP_MEMORY_SCOPE_AGENT);
}

struct PP {
  const ushort_t *w0e_hi, *w0e_lo, *w1e_hi, *w1e_lo;
  const ushort_t *w0d_hi, *w0d_lo, *w1d_hi, *w1d_lo;
  ushort_t *h0hi0, *h0hi1, *h0lo0, *h0lo1;
  ushort_t *h1hi0, *h1hi1, *h1lo0, *h1lo1;
  const float *be0, *be1, *bd0, *bd1, *wxe, *wxd;
  const float *x, *headW, *hb;
  float *hpart;        // [n][32] per-mb head partials
  float *out;
  unsigned *slots;     // [256] completed-phase counters
  unsigned *xcdcnt;    // [8] per-XCD claim counters
};

struct Ph {
  const ushort_t *w0hi, *w0lo, *w1hi, *w1lo;
  const ushort_t *b0hi, *b0lo, *b1hi, *b1lo;
  const float *bias0, *wx0, *bias1;
  ushort_t *H0hi, *H0lo, *H1hi, *H1lo;
  int has0, has1, nkt;
  int xmode;    // 0: x[:,tcol]; 1: head from hpart
  int tcol;
  int outcol;   // >=0: lanes wm==0 write out[:,outcol] = xv
  int do_head;  // L1 epilogue stores head partials
};

__global__ __launch_bounds__(256) void lstm_persist(PP P) {
  __shared__ __align__(16) ushort_t sm[2 * BUFS];     // 96 KB
  __shared__ ushort_t hshi[64 * 18];
  __shared__ ushort_t hslo[64 * 18];
  __shared__ unsigned sclaim;

  const int tid = threadIdx.x;
  const int bx = blockIdx.x;

  // ---- XCD discovery + tile claim: weights become XCD-L2-resident ----
  // Each XCD hosts exactly 32 blocks (LDS forces 1 block/CU, 256 blocks, 32 CU/XCD).
  // XCD x covers m-tiles {4x..4x+3} x n-tiles {0..7}: 1.5 MB weight slice < 4 MB L2.
  if (tid == 0) {
    unsigned xcc;
    asm volatile("s_getreg_b32 %0, hwreg(HW_REG_XCC_ID)" : "=s"(xcc));
    xcc &= 7u;
    unsigned slot = atomicAdd(&P.xcdcnt[xcc], 1u) & 31u;
    sclaim = (xcc << 5) | slot;
  }
  __syncthreads();
  const unsigned cl = sclaim;
  const int nb = cl & 7;                 // n-tile (batch group)
  const int mb = (cl >> 5) * 4 + ((cl >> 3) & 3);   // m-tile 0..31
  const int m0blk = mb * 64;
  const int n0blk = nb * 64;

  const int wv = tid >> 6;
  const int ln = tid & 63;
  const int l31 = ln & 31;
  const int half = ln >> 5;
  const int wm = wv & 1, wn = wv >> 1;
  const int m0w = wm * 32, n0w = wn * 32;
  const int r8 = ln >> 3;
  const int k8s = (ln & 7) ^ r8;
  const int ng = n0blk + n0w + l31;

  ushort_t* h0hi[2] = {P.h0hi0, P.h0hi1};
  ushort_t* h0lo[2] = {P.h0lo0, P.h0lo1};
  ushort_t* h1hi[2] = {P.h1hi0, P.h1hi1};
  ushort_t* h1lo[2] = {P.h1lo0, P.h1lo1};

  float cr0[4] = {0.f, 0.f, 0.f, 0.f};
  float cr1[4] = {0.f, 0.f, 0.f, 0.f};
  unsigned phase = 0;

  auto gbar = [&]() {
    __builtin_amdgcn_s_waitcnt(0);      // all my VMEM (atomic stores) done at L3
    __syncthreads();
    ++phase;
    if (tid == 0) astu(&P.slots[bx], phase);
    asm volatile("" ::: "memory");
    while (aldu(&P.slots[tid]) < phase) __builtin_amdgcn_s_sleep(2);
    asm volatile("" ::: "memory");
    __syncthreads();
  };

  auto cell_epi = [&](floatx16& acc, float* cr, const float* bias, const float* wx,
                      bool useX, float xv, ushort_t* Hhi, ushort_t* Hlo) {
    #pragma unroll
    for (int rg = 0; rg < 4; ++rg) {
      const int jl = wm * 8 + rg * 2 + half;
      const int jg = mb * 16 + jl;
      const float4 bi = *(const float4*)&bias[jg * 4];
      float gi = acc[rg * 4 + 0] + bi.x;
      float gf = acc[rg * 4 + 1] + bi.y;
      float gg = acc[rg * 4 + 2] + bi.z;
      float go = acc[rg * 4 + 3] + bi.w;
      if (useX) {
        const float4 wx4 = *(const float4*)&wx[jg * 4];
        gi += xv * wx4.x; gf += xv * wx4.y; gg += xv * wx4.z; go += xv * wx4.w;
      }
      const float i_ = sig_(gi), f_ = sig_(gf), g_ = tanhf(gg), o_ = sig_(go);
      const float cn = f_ * cr[rg] + i_ * g_;
      cr[rg] = cn;
      const float hn = o_ * tanhf(cn);
      const ushort_t hhi = f2bf(hn);
      const ushort_t hlo = f2bf(hn - bf2f(hhi));
      const int nbk = n0w + l31;
      hshi[nbk * 18 + jl] = hhi;
      hslo[nbk * 18 + jl] = hlo;
    }
    __syncthreads();
    {
      const int nbk = tid >> 2, jq = (tid & 3) * 4;
      ull hv = (ull)hshi[nbk * 18 + jq] | ((ull)hshi[nbk * 18 + jq + 1] << 16)
             | ((ull)hshi[nbk * 18 + jq + 2] << 32) | ((ull)hshi[nbk * 18 + jq + 3] << 48);
      ull lv = (ull)hslo[nbk * 18 + jq] | ((ull)hslo[nbk * 18 + jq + 1] << 16)
             | ((ull)hslo[nbk * 18 + jq + 2] << 32) | ((ull)hslo[nbk * 18 + jq + 3] << 48);
      ast64(&Hhi[(size_t)(n0blk + nbk) * kH + mb * 16 + jq], hv);
      ast64(&Hlo[(size_t)(n0blk + nbk) * kH + mb * 16 + jq], lv);
    }
  };

  auto run_phase = [&](const Ph& ph) {
    floatx16 acc0, acc1;
    #pragma unroll
    for (int i = 0; i < 16; ++i) { acc0[i] = 0.f; acc1[i] = 0.f; }

    auto dma_kt = [&](int kt, int buf) {
      if (wv <= 1) {
        ushort_t* bb = &sm[buf * BUFS];
        if (ph.has0 && kt < 8) {
          const ushort_t* w = wv ? ph.w0lo : ph.w0hi;
          const ushort_t* g0 = w + (size_t)(m0blk + r8) * 512 + kt * 64 + k8s * 8;
          ushort_t* lb = bb + P_A0 + wv * 4096;
          #pragma unroll
          for (int i = 0; i < 8; ++i) async16(g0 + (size_t)i * 8 * 512, lb + i * 512);
        }
        if (ph.has1) {
          const ushort_t* w = wv ? ph.w1lo : ph.w1hi;
          const ushort_t* g0 = w + (size_t)(m0blk + r8) * 1024 + kt * 64 + k8s * 8;
          ushort_t* lb = bb + P_A1 + wv * 4096;
          #pragma unroll
          for (int i = 0; i < 8; ++i) async16(g0 + (size_t)i * 8 * 1024, lb + i * 512);
        }
      }
    };
    auto bload = [&](int kt, ull* br) {
      if (wv >= 2) {
        const ushort_t* s = (kt < 8) ? (wv == 2 ? ph.b0hi : ph.b0lo)
                                     : (wv == 2 ? ph.b1hi : ph.b1lo);
        const int col0 = (kt & 7) * 64;
        const ushort_t* g0 = s + (size_t)(n0blk + r8) * kH + col0 + k8s * 8;
        #pragma unroll
        for (int i = 0; i < 8; ++i) {
          const ushort_t* gp = g0 + (size_t)i * 8 * kH;
          br[2 * i]     = ald64(gp);
          br[2 * i + 1] = ald64(gp + 4);
        }
      }
    };
    auto bwrite = [&](int buf, const ull* br) {
      if (wv >= 2) {
        ushort_t* lb = &sm[buf * BUFS] + P_B + (wv - 2) * 4096;
        #pragma unroll
        for (int i = 0; i < 8; ++i) {
          int4 v;
          v.x = (int)(unsigned)br[2 * i];
          v.y = (int)(unsigned)(br[2 * i] >> 32);
          v.z = (int)(unsigned)br[2 * i + 1];
          v.w = (int)(unsigned)(br[2 * i + 1] >> 32);
          *(int4*)(lb + i * 512 + ln * 8) = v;
        }
      }
    };
    auto compute = [&](int kt, int buf) {
      const ushort_t* base = &sm[buf * BUFS];
      #pragma unroll
      for (int ks = 0; ks < 4; ++ks) {
        const int k8 = ks * 2 + half;
        const int sw = k8 ^ (l31 & 7);
        const int qa = ((m0w + l31) * 8 + sw) * 8;
        const int qb = ((n0w + l31) * 8 + sw) * 8;
        short8 bhi = *(const short8*)(base + P_B + qb);
        short8 blo = *(const short8*)(base + P_B + 4096 + qb);
        if (ph.has0 && kt < 8) {
          short8 ahi = *(const short8*)(base + P_A0 + qa);
          short8 alo = *(const short8*)(base + P_A0 + 4096 + qa);
          acc0 = __builtin_amdgcn_mfma_f32_32x32x16_bf16(alo, bhi, acc0, 0, 0, 0);
          acc0 = __builtin_amdgcn_mfma_f32_32x32x16_bf16(ahi, blo, acc0, 0, 0, 0);
          acc0 = __builtin_amdgcn_mfma_f32_32x32x16_bf16(ahi, bhi, acc0, 0, 0, 0);
        }
        if (ph.has1) {
          short8 ahi = *(const short8*)(base + P_A1 + qa);
          short8 alo = *(const short8*)(base + P_A1 + 4096 + qa);
          acc1 = __builtin_amdgcn_mfma_f32_32x32x16_bf16(alo, bhi, acc1, 0, 0, 0);
          acc1 = __builtin_amdgcn_mfma_f32_32x32x16_bf16(ahi, blo, acc1, 0, 0, 0);
          acc1 = __builtin_amdgcn_mfma_f32_32x32x16_bf16(ahi, bhi, acc1, 0, 0, 0);
        }
      }
    };

    ull br[16];
    bload(0, br);
    dma_kt(0, 0);
    bwrite(0, br);
    __syncthreads();
    for (int kt = 0; kt < ph.nkt; ++kt) {
      const int cur = kt & 1, nxt = cur ^ 1;
      const bool more = (kt + 1) < ph.nkt;
      if (more) { bload(kt + 1, br); dma_kt(kt + 1, nxt); }
      compute(kt, cur);
      if (more) bwrite(nxt, br);
      __syncthreads();
    }

    if (ph.has0) {
      float xv;
      if (ph.xmode == 0) {
        xv = P.x[(size_t)ng * kT + ph.tcol];
      } else {
        float s = P.hb[0];
        const float* hp = &P.hpart[(size_t)ng * 32];
        #pragma unroll
        for (int i = 0; i < 16; ++i) {
          ull v = ald64(hp + 2 * i);
          s += __builtin_bit_cast(float, (unsigned)v)
             + __builtin_bit_cast(float, (unsigned)(v >> 32));
        }
        xv = s;
      }
      cell_epi(acc0, cr0, ph.bias0, ph.wx0, true, xv, ph.H0hi, ph.H0lo);
      if (ph.outcol >= 0 && wm == 0)
        P.out[(size_t)ng * kHor + ph.outcol] = xv;
      __syncthreads();
    }
    if (ph.has1) {
      cell_epi(acc1, cr1, ph.bias1, nullptr, false, 0.f, ph.H1hi, ph.H1lo);
      if (ph.do_head && tid < 64) {
        float s = 0.f;
        #pragma unroll
        for (int jb = 0; jb < 16; ++jb)
          s += (bf2f(hshi[tid * 18 + jb]) + bf2f(hslo[tid * 18 + jb]))
               * P.headW[mb * 16 + jb];
        astf(&P.hpart[(size_t)(n0blk + tid) * 32 + mb], s);
      }
      __syncthreads();
    }
  };

  // ---------- encoder: merged wavefront L0[p] || L1[p-1] ----------
  for (int p = 0; p <= 256; ++p) {
    const int rd = p & 1, wr = rd ^ 1;
    Ph ph = {};
    ph.has0 = (p < 256); ph.has1 = (p >= 1);
    ph.nkt = ph.has1 ? 16 : 8;
    ph.w0hi = P.w0e_hi; ph.w0lo = P.w0e_lo;
    ph.w1hi = P.w1e_hi; ph.w1lo = P.w1e_lo;
    ph.b0hi = h0hi[rd]; ph.b0lo = h0lo[rd];
    ph.b1hi = h1hi[rd]; ph.b1lo = h1lo[rd];
    ph.bias0 = P.be0; ph.wx0 = P.wxe; ph.bias1 = P.be1;
    ph.H0hi = h0hi[wr]; ph.H0lo = h0lo[wr];
    ph.H1hi = h1hi[wr]; ph.H1lo = h1lo[wr];
    ph.xmode = 0; ph.tcol = (p < 256) ? p : 0;
    ph.outcol = -1; ph.do_head = 0;
    run_phase(ph);
    gbar();
  }
  // h0 final parity 0, h1 final parity 1

  // ---------- decoder ----------
  for (int t = 0; t < kHor; ++t) {
    const int r0 = t & 1, w0 = r0 ^ 1;
    const int r1 = (t + 1) & 1, w1 = t & 1;
    {
      Ph a = {};
      a.has0 = 1; a.has1 = 0; a.nkt = 8;
      a.w0hi = P.w0d_hi; a.w0lo = P.w0d_lo;
      a.b0hi = h0hi[r0]; a.b0lo = h0lo[r0];
      a.bias0 = P.bd0; a.wx0 = P.wxd;
      a.H0hi = h0hi[w0]; a.H0lo = h0lo[w0];
      a.xmode = (t == 0) ? 0 : 1; a.tcol = 255;
      a.outcol = (t >= 1) ? (t - 1) : -1;
      a.do_head = 0;
      run_phase(a);
      gbar();
    }
    {
      Ph b = {};
      b.has0 = 0; b.has1 = 1; b.nkt = 16;
      b.w1hi = P.w1d_hi; b.w1lo = P.w1d_lo;
      b.b0hi = h0hi[w0]; b.b0lo = h0lo[w0];
      b.b1hi = h1hi[r1]; b.b1lo = h1lo[r1];
      b.bias1 = P.bd1;
      b.H1hi = h1hi[w1]; b.H1lo = h1lo[w1];
      b.xmode = 0; b.tcol = 0; b.outcol = -1; b.do_head = 1;
      run_phase(b);
      gbar();
    }
  }

  // final output column 63
  if (mb == 0 && tid < 64) {
    const int n = n0blk + tid;
    float s = P.hb[0];
    const float* hp = &P.hpart[(size_t)n * 32];
    #pragma unroll
    for (int i = 0; i < 16; ++i) {
      ull v = ald64(hp + 2 * i);
      s += __builtin_bit_cast(float, (unsigned)v)
         + __builtin_bit_cast(float, (unsigned)(v >> 32));
    }
    P.out[(size_t)n * kHor + 63] = s;
  }
}

// ---- prep kernels ----
__global__ void prep_w(const float* __restrict__ s0, const float* __restrict__ s1,
                       ushort_t* __restrict__ hi, ushort_t* __restrict__ lo, int Kw) {
  const int k = blockIdx.x * 256 + threadIdx.x;
  const int r = blockIdx.y;                 // packed row j*4+g
  const int j = r >> 2, g = r & 3;
  const int srow = g * kH + j;
  const float v = (k < kH) ? s0[(size_t)srow * kH + k]
                           : s1[(size_t)srow * kH + (k - kH)];
  const ushort_t h = f2bf(v);
  const ushort_t l = f2bf(v - bf2f(h));
  hi[(size_t)r * Kw + k] = h;
  lo[(size_t)r * Kw + k] = l;
}

__global__ void prep_vec(const float* __restrict__ src, float* __restrict__ dst) {
  const int t = blockIdx.x * 256 + threadIdx.x;   // 2048
  const int j = t >> 2, g = t & 3;
  dst[t] = src[g * kH + j];
}

__global__ void init_zero(ushort_t* p0, ushort_t* p1, ushort_t* p2, ushort_t* p3,
                          ushort_t* p4, ushort_t* p5, ushort_t* p6, ushort_t* p7,
                          unsigned* slots, unsigned* xcdcnt) {
  const int i = blockIdx.x * 256 + threadIdx.x;   // 262144
  p0[i] = 0; p1[i] = 0; p2[i] = 0; p3[i] = 0;
  p4[i] = 0; p5[i] = 0; p6[i] = 0; p7[i] = 0;
  if (i < NBLK) slots[i] = 0u;
  if (i < 8) xcdcnt[i] = 0u;
}

extern "C" void kernel_launch(void* const* d_in, const int* in_sizes, int n_in,
                              void* d_out, int out_size, void* d_ws, size_t ws_size,
                              hipStream_t stream) {
  const float* x     = (const float*)d_in[0];
  const float* eWih0 = (const float*)d_in[1];
  const float* eWhh0 = (const float*)d_in[2];
  const float* eb0   = (const float*)d_in[3];
  const float* eWih1 = (const float*)d_in[4];
  const float* eWhh1 = (const float*)d_in[5];
  const float* eb1   = (const float*)d_in[6];
  const float* dWih0 = (const float*)d_in[7];
  const float* dWhh0 = (const float*)d_in[8];
  const float* db0   = (const float*)d_in[9];
  const float* dWih1 = (const float*)d_in[10];
  const float* dWhh1 = (const float*)d_in[11];
  const float* db1   = (const float*)d_in[12];
  const float* hW    = (const float*)d_in[13];
  const float* hb    = (const float*)d_in[14];
  float* out = (float*)d_out;

  char* w = (char*)d_ws;
  size_t off = 0;
  auto aus = [&](size_t n) { ushort_t* p = (ushort_t*)(w + off); off += ((n * 2 + 255) & ~(size_t)255); return p; };
  auto afl = [&](size_t n) { float* p = (float*)(w + off); off += ((n * 4 + 255) & ~(size_t)255); return p; };

  ushort_t* w0e_hi = aus((size_t)NG * 512);  ushort_t* w0e_lo = aus((size_t)NG * 512);
  ushort_t* w1e_hi = aus((size_t)NG * 1024); ushort_t* w1e_lo = aus((size_t)NG * 1024);
  ushort_t* w0d_hi = aus((size_t)NG * 512);  ushort_t* w0d_lo = aus((size_t)NG * 512);
  ushort_t* w1d_hi = aus((size_t)NG * 1024); ushort_t* w1d_lo = aus((size_t)NG * 1024);
  ushort_t* h0hi[2] = {aus(kB * kH), aus(kB * kH)};
  ushort_t* h0lo[2] = {aus(kB * kH), aus(kB * kH)};
  ushort_t* h1hi[2] = {aus(kB * kH), aus(kB * kH)};
  ushort_t* h1lo[2] = {aus(kB * kH), aus(kB * kH)};
  float* be0 = afl(NG); float* be1 = afl(NG);
  float* bd0 = afl(NG); float* bd1 = afl(NG);
  float* wxe = afl(NG); float* wxd = afl(NG);
  float* hpart = afl((size_t)kB * 32);
  unsigned* slots = (unsigned*)afl(NBLK);
  unsigned* xcdcnt = (unsigned*)afl(8);

  prep_w<<<dim3(2, NG), 256, 0, stream>>>(eWhh0, eWhh0, w0e_hi, w0e_lo, 512);
  prep_w<<<dim3(4, NG), 256, 0, stream>>>(eWih1, eWhh1, w1e_hi, w1e_lo, 1024);
  prep_w<<<dim3(2, NG), 256, 0, stream>>>(dWhh0, dWhh0, w0d_hi, w0d_lo, 512);
  prep_w<<<dim3(4, NG), 256, 0, stream>>>(dWih1, dWhh1, w1d_hi, w1d_lo, 1024);
  prep_vec<<<8, 256, 0, stream>>>(eb0, be0);
  prep_vec<<<8, 256, 0, stream>>>(eb1, be1);
  prep_vec<<<8, 256, 0, stream>>>(db0, bd0);
  prep_vec<<<8, 256, 0, stream>>>(db1, bd1);
  prep_vec<<<8, 256, 0, stream>>>(eWih0, wxe);
  prep_vec<<<8, 256, 0, stream>>>(dWih0, wxd);
  init_zero<<<1024, 256, 0, stream>>>(h0hi[0], h0hi[1], h0lo[0], h0lo[1],
                                      h1hi[0], h1hi[1], h1lo[0], h1lo[1],
                                      slots, xcdcnt);

  PP P;
  P.w0e_hi = w0e_hi; P.w0e_lo = w0e_lo; P.w1e_hi = w1e_hi; P.w1e_lo = w1e_lo;
  P.w0d_hi = w0d_hi; P.w0d_lo = w0d_lo; P.w1d_hi = w1d_hi; P.w1d_lo = w1d_lo;
  P.h0hi0 = h0hi[0]; P.h0hi1 = h0hi[1]; P.h0lo0 = h0lo[0]; P.h0lo1 = h0lo[1];
  P.h1hi0 = h1hi[0]; P.h1hi1 = h1hi[1]; P.h1lo0 = h1lo[0]; P.h1lo1 = h1lo[1];
  P.be0 = be0; P.be1 = be1; P.bd0 = bd0; P.bd1 = bd1; P.wxe = wxe; P.wxd = wxd;
  P.x = x; P.headW = hW; P.hb = hb;
  P.hpart = hpart; P.out = out; P.slots = slots;
  P.xcdcnt = xcdcnt;

  lstm_persist<<<dim3(NBLK), dim3(256), 0, stream>>>(P);
}